// Round 9
// baseline (299.944 us; speedup 1.0000x reference)
//
#include <hip/hip_runtime.h>
#include <stdint.h>

#define DEV __device__ __forceinline__

typedef unsigned short u16;
typedef __bf16 bf16x8 __attribute__((ext_vector_type(8)));
typedef float f32x4 __attribute__((ext_vector_type(4)));
typedef u16 u16x8 __attribute__((ext_vector_type(8)));

#define MFMA_BF16(A, B, C) __builtin_amdgcn_mfma_f32_16x16x32_bf16(A, B, C, 0, 0, 0)
#define EXP2(x) __builtin_amdgcn_exp2f(x)

DEV u16 f2bf(float f) {
    unsigned x;
    __builtin_memcpy(&x, &f, 4);
    unsigned r = (x + 0x7fffu + ((x >> 16) & 1u)) >> 16;  // RNE
    return (u16)r;
}

DEV u16 f2bf_fast(float f) {  // round-half-up; 2 VALU ops, used in attn hot loop
    unsigned x;
    __builtin_memcpy(&x, &f, 4);
    return (u16)((x + 0x8000u) >> 16);
}

DEV void storeC(u16* p, float v) { *p = f2bf(v); }
DEV void storeC(float* p, float v) { *p = v; }

// async global->LDS, 16B per lane. LDS dest must be wave-uniform base + lane*16.
DEV void async_copy16(const u16* g, u16* l) {
    __builtin_amdgcn_global_load_lds(
        (__attribute__((address_space(1))) unsigned int*)g,
        (__attribute__((address_space(3))) unsigned int*)l, 16, 0, 0);
}

// ---------------------------------------------------------------------------
// fused fp32 -> bf16 conversion of x | wqkv | wout into one contiguous dest.
// ---------------------------------------------------------------------------
constexpr int N_X = 8192 * 1024, N_WQ = 3072 * 1024, N_WO = 1024 * 1024;

__global__ __launch_bounds__(256)
void cvt_all(const float* __restrict__ x, const float* __restrict__ wq,
             const float* __restrict__ wo, u16* __restrict__ out) {
    const int i = (blockIdx.x * 256 + threadIdx.x) * 4;
    const float* src;
    if (i < N_X) src = x + i;
    else if (i < N_X + N_WQ) src = wq + (i - N_X);
    else src = wo + (i - N_X - N_WQ);
    const float4 v = *(const float4*)src;
    ushort4 o;
    o.x = f2bf(v.x);
    o.y = f2bf(v.y);
    o.z = f2bf(v.z);
    o.w = f2bf(v.w);
    *(ushort4*)(out + i) = o;
}

// ---------------------------------------------------------------------------
// C[M,N] = A[M,K] * Bw[N,K]^T + bias[N]; A,Bw bf16, bias fp32, fp32 accum.
// 128x128 tile, BK=64 as two 32-wide panels. EXACT r0 kernel — FROZEN.
// VSPLIT: cols >= 2048 (the V third of QKV) stored TRANSPOSED into vT.
// ---------------------------------------------------------------------------
template <typename OT, bool VSPLIT>
__global__ __launch_bounds__(256, 2)
void gemm_bt_bias(const u16* __restrict__ A, const u16* __restrict__ Bw,
                  const float* __restrict__ bias, OT* __restrict__ C,
                  u16* __restrict__ vT, int M, int N, int K) {
    __shared__ __attribute__((aligned(16))) u16 sA[2][128 * 32];
    __shared__ __attribute__((aligned(16))) u16 sB[2][128 * 32];

    const int tid  = threadIdx.x;
    const int lane = tid & 63;
    const int wave = tid >> 6;
    const int m0 = blockIdx.x * 128;   // M on x: XCD-local A reuse
    const int n0 = blockIdx.y * 128;
    const int wm = (wave & 1) * 64;
    const int wn = (wave >> 1) * 64;
    const int fr = lane & 15;
    const int q4 = lane >> 4;

    const int r0 = tid >> 2;
    const int c0 = (tid & 3) * 8;
    const u16* gA0 = A + (size_t)(m0 + r0) * K + c0;
    const u16* gA1 = A + (size_t)(m0 + 64 + r0) * K + c0;
    const u16* gB0 = Bw + (size_t)(n0 + r0) * K + c0;
    const u16* gB1 = Bw + (size_t)(n0 + 64 + r0) * K + c0;

    f32x4 acc[4][4];
#pragma unroll
    for (int i = 0; i < 4; i++)
#pragma unroll
        for (int j = 0; j < 4; j++) acc[i][j] = (f32x4){0.f, 0.f, 0.f, 0.f};

    for (int k0 = 0; k0 < K; k0 += 64) {
#pragma unroll
        for (int p = 0; p < 2; ++p) {  // two 32-wide K panels
            async_copy16(gA0 + k0 + p * 32, &sA[p][tid * 8]);
            async_copy16(gA1 + k0 + p * 32, &sA[p][2048 + tid * 8]);
            async_copy16(gB0 + k0 + p * 32, &sB[p][tid * 8]);
            async_copy16(gB1 + k0 + p * 32, &sB[p][2048 + tid * 8]);
        }
        __syncthreads();

#pragma unroll
        for (int p = 0; p < 2; ++p) {
            bf16x8 af[4], bfr[4];
#pragma unroll
            for (int i = 0; i < 4; i++)
                af[i] = *(const bf16x8*)&sA[p][(wm + i * 16 + fr) * 32 + q4 * 8];
#pragma unroll
            for (int j = 0; j < 4; j++)
                bfr[j] = *(const bf16x8*)&sB[p][(wn + j * 16 + fr) * 32 + q4 * 8];
#pragma unroll
            for (int i = 0; i < 4; i++)
#pragma unroll
                for (int j = 0; j < 4; j++)
                    acc[i][j] = MFMA_BF16(af[i], bfr[j], acc[i][j]);
        }
        __syncthreads();
    }

    // epilogue: C/D layout col=lane&15, row=quad*4+reg  [verified m89/m91]
#pragma unroll
    for (int j = 0; j < 4; j++) {
        const int col = n0 + wn + j * 16 + fr;
        const float bv = bias[col];
        if (VSPLIT && col >= 2048) {  // wave-uniform: col/16 uniform across fr
#pragma unroll
            for (int i = 0; i < 4; i++) {
                const int row = m0 + wm + i * 16 + q4 * 4;
                ushort4 o;
                o.x = f2bf(acc[i][j][0] + bv);
                o.y = f2bf(acc[i][j][1] + bv);
                o.z = f2bf(acc[i][j][2] + bv);
                o.w = f2bf(acc[i][j][3] + bv);
                *(ushort4*)&vT[(size_t)(col - 2048) * 8192 + row] = o;
            }
        } else {
#pragma unroll
            for (int i = 0; i < 4; i++) {
                const int row = m0 + wm + i * 16 + q4 * 4;
#pragma unroll
                for (int r = 0; r < 4; r++)
                    storeC(&C[(size_t)(row + r) * N + col], acc[i][j][r] + bv);
            }
        }
    }
}

// ---------------------------------------------------------------------------
// Flash attention, causal, S^T/O^T, FOUR CAUSAL-BALANCED Q-TILES, fixed-point
// softmax. This round: BARRIER-FREE. K/V fragments are read per-wave straight
// from L2 into registers (no K/V LDS, no staging, no __syncthreads anywhere):
// r8 proved conflicts/barrier-count aren't the chain — the lock-step coupling
// is. Each wave free-runs; 4x redundant K/V reads are L2/L1-resident
// (~0.95 GB total ≈ 14.6 TB/s << 34.5 TB/s L2 ceiling; kf0/kf1 of a row share
// a 128B line; the block's 4 waves share L1). Per-tile processing keeps S
// registers live one tile at a time (peak ~200 VGPR). sP stays in LDS
// (wave-local, DS in-order — needs no barrier).
// ---------------------------------------------------------------------------
constexpr int Lc = 2048, Dc = 1024;

__global__ __launch_bounds__(256, 2)
void attn_fa(const u16* __restrict__ qkv, const u16* __restrict__ vT,
             u16* __restrict__ outb) {
    __shared__ __attribute__((aligned(16))) u16 sP[4][4][16 * 72];  // [wave][tile][q][key]

    const int tid  = threadIdx.x;
    const int lane = tid & 63;
    const int wave = tid >> 6;
    const int fr = lane & 15;
    const int q4 = lane >> 4;

    const int id = blockIdx.x;               // 0..511
    const int g  = (id & 7) + 8 * (id >> 6); // (b,h) group; XCD = g & 7
    const int bx = (id >> 3) & 7;            // 0..7
    const int h = g & 15;
    const int b = g >> 4;
    const int qA = bx, qB = 15 - bx, qC = 16 + bx, qD = 31 - bx;

    constexpr float CEXP = 0.18033688011112042f;   // 0.125 * log2(e)
    constexpr float MOFF = 16.0f * CEXP;           // fixed rescale point m=16

    bf16x8 qfA[2], qfB[2], qfC[2], qfD[2];
#define LOADQ(qf, qblk)                                                     \
    {                                                                       \
        const int qrow = (qblk) * 64 + wave * 16 + fr;                      \
        const u16* qp = qkv + ((size_t)(b * Lc + qrow) * 3) * Dc + h * 64;  \
        qf[0] = *(const bf16x8*)(qp + q4 * 8);                              \
        qf[1] = *(const bf16x8*)(qp + 32 + q4 * 8);                         \
    }
    LOADQ(qfA, qA) LOADQ(qfB, qB) LOADQ(qfC, qC) LOADQ(qfD, qD)
#undef LOADQ

    f32x4 oA[4], oB[4], oC[4], oD[4];
#pragma unroll
    for (int t = 0; t < 4; t++) {
        oA[t] = (f32x4){0.f, 0.f, 0.f, 0.f};
        oB[t] = (f32x4){0.f, 0.f, 0.f, 0.f};
        oC[t] = (f32x4){0.f, 0.f, 0.f, 0.f};
        oD[t] = (f32x4){0.f, 0.f, 0.f, 0.f};
    }
    float lA = 0.f, lB = 0.f, lC = 0.f, lD = 0.f;  // per-lane partial sums

    const int q_local = wave * 16 + fr;

    // per-wave fragment bases (no LDS staging at all)
    const u16* kb = qkv + ((size_t)(b * Lc) * 3 + 1) * Dc + h * 64 +
                    (size_t)(fr)*3072 + q4 * 8;           // + (jb*64 + t*16)*3072
    const u16* vb = vT + (size_t)(h * 64 + fr) * 8192 + b * Lc + q4 * 8;  // + t*16*8192 + jb*64

    u16* sPA = &sP[wave][0][0];
    u16* sPB = &sP[wave][1][0];
    u16* sPC = &sP[wave][2][0];
    u16* sPD = &sP[wave][3][0];

    // per-tile: S^T = K Q^T (kf in regs), fixed-point softmax, pack into sP.
#define DO_TILE(qf, lS, sPp, qblk)                                          \
    {                                                                       \
        f32x4 S[4];                                                         \
        _Pragma("unroll") for (int t = 0; t < 4; t++) {                     \
            S[t] = (f32x4){0.f, 0.f, 0.f, 0.f};                             \
            S[t] = MFMA_BF16(kf[t][0], qf[0], S[t]);                        \
            S[t] = MFMA_BF16(kf[t][1], qf[1], S[t]);                        \
        }                                                                   \
        if (jb == (qblk)) {                                                 \
            _Pragma("unroll") for (int t = 0; t < 4; t++)                   \
                _Pragma("unroll") for (int r = 0; r < 4; r++)               \
                    if (t * 16 + q4 * 4 + r > q_local) S[t][r] = -1e30f;    \
        }                                                                   \
        _Pragma("unroll") for (int t = 0; t < 4; t++) {                     \
            _Pragma("unroll") for (int r = 0; r < 4; r++) {                 \
                const float p = EXP2(__builtin_fmaf(S[t][r], CEXP, -MOFF)); \
                S[t][r] = p;                                                \
                lS += p;                                                    \
            }                                                               \
            ushort4 o;                                                      \
            o.x = f2bf_fast(S[t][0]);                                       \
            o.y = f2bf_fast(S[t][1]);                                       \
            o.z = f2bf_fast(S[t][2]);                                       \
            o.w = f2bf_fast(S[t][3]);                                       \
            *(ushort4*)&sPp[fr * 72 + t * 16 + q4 * 4] = o;                 \
        }                                                                   \
    }

    for (int jb = 0; jb <= qD; ++jb) {
        const bool doA = (jb <= qA);  // wave-uniform
        const bool doB = (jb <= qB);
        const bool doC = (jb <= qC);

        // K fragments (A-operand of S^T = K Q^T): row = key, k = d
        bf16x8 kf[4][2];
        const u16* kt = kb + (size_t)(jb * 64) * 3072;
#pragma unroll
        for (int t = 0; t < 4; t++) {
            kf[t][0] = *(const bf16x8*)(kt + (size_t)(t * 16) * 3072);
            kf[t][1] = *(const bf16x8*)(kt + (size_t)(t * 16) * 3072 + 32);
        }
        // V fragments (A-operand of O^T = V^T P^T): row = d, k = key.
        // Issued here so their L2 latency hides under QK^T + softmax below.
        bf16x8 vf[4][2];
        const u16* vt = vb + jb * 64;
#pragma unroll
        for (int t = 0; t < 4; t++) {
#pragma unroll
            for (int ks = 0; ks < 2; ks++)
                vf[t][ks] = *(const bf16x8*)(vt + (size_t)(t * 16) * 8192 + ks * 32);
        }

        DO_TILE(qfD, lD, sPD, qD);
        if (doC) DO_TILE(qfC, lC, sPC, qC);
        if (doB) DO_TILE(qfB, lB, sPB, qB);
        if (doA) DO_TILE(qfA, lA, sPA, qA);

        // O^T += V^T P^T (vf already resident; sP wave-local, DS in-order)
#pragma unroll
        for (int ks = 0; ks < 2; ++ks) {
            const bf16x8 pfD = *(const bf16x8*)&sPD[fr * 72 + ks * 32 + q4 * 8];
            bf16x8 pfC, pfB, pfA;
            if (doC) pfC = *(const bf16x8*)&sPC[fr * 72 + ks * 32 + q4 * 8];
            if (doB) pfB = *(const bf16x8*)&sPB[fr * 72 + ks * 32 + q4 * 8];
            if (doA) pfA = *(const bf16x8*)&sPA[fr * 72 + ks * 32 + q4 * 8];
#pragma unroll
            for (int t = 0; t < 4; t++) {
                oD[t] = MFMA_BF16(vf[t][ks], pfD, oD[t]);
                if (doC) oC[t] = MFMA_BF16(vf[t][ks], pfC, oC[t]);
                if (doB) oB[t] = MFMA_BF16(vf[t][ks], pfB, oB[t]);
                if (doA) oA[t] = MFMA_BF16(vf[t][ks], pfA, oA[t]);
            }
        }
    }
#undef DO_TILE

    // epilogue: reduce per-lane l once, then O^T -> packed ushort4
#define WR_OUT(oS, lS, qblk)                                                      \
    {                                                                             \
        float lt = lS;                                                            \
        lt += __shfl_xor(lt, 16);                                                 \
        lt += __shfl_xor(lt, 32);                                                 \
        const float rl = 1.0f / lt;                                               \
        u16* orow =                                                               \
            outb + (size_t)(b * Lc + (qblk) * 64 + wave * 16 + fr) * Dc + h * 64; \
        _Pragma("unroll") for (int t = 0; t < 4; t++) {                           \
            ushort4 o;                                                            \
            o.x = f2bf(oS[t][0] * rl);                                            \
            o.y = f2bf(oS[t][1] * rl);                                            \
            o.z = f2bf(oS[t][2] * rl);                                            \
            o.w = f2bf(oS[t][3] * rl);                                            \
            *(ushort4*)(orow + t * 16 + q4 * 4) = o;                              \
        }                                                                         \
    }
    WR_OUT(oA, lA, qA)
    WR_OUT(oB, lB, qB)
    WR_OUT(oC, lC, qC)
    WR_OUT(oD, lD, qD)
#undef WR_OUT
}

// ---------------------------------------------------------------------------
extern "C" void kernel_launch(void* const* d_in, const int* in_sizes, int n_in,
                              void* d_out, int out_size, void* d_ws, size_t ws_size,
                              hipStream_t stream) {
    const float* x    = (const float*)d_in[0];  // [4,2048,1024] fp32
    const float* wqkv = (const float*)d_in[1];  // [3072,1024]
    const float* bqkv = (const float*)d_in[2];  // [3072]
    const float* wout = (const float*)d_in[3];  // [1024,1024]
    const float* bout = (const float*)d_in[4];  // [1024]
    float* out = (float*)d_out;                 // [4,2048,1024] fp32

    u16* qkv    = (u16*)d_ws;                       // [8192,3072] bf16 (V third unused)
    u16* attn   = qkv + (size_t)8192 * 3072;        // [8192,1024] bf16
    u16* xbf    = attn + (size_t)8192 * 1024;       // [8192,1024] bf16
    u16* wqkvbf = xbf + (size_t)8192 * 1024;        // [3072,1024] bf16
    u16* woutbf = wqkvbf + (size_t)3072 * 1024;     // [1024,1024] bf16
    u16* vT     = woutbf + (size_t)1024 * 1024;     // [1024, 8192] bf16 (V transposed)

    dim3 blk(256);
    cvt_all<<<(N_X + N_WQ + N_WO) / 1024, blk, 0, stream>>>(x, wqkv, wout, xbf);

    gemm_bt_bias<u16, true><<<dim3(8192 / 128, 3072 / 128), blk, 0, stream>>>(
        xbf, wqkvbf, bqkv, qkv, vT, 8192, 3072, 1024);
    attn_fa<<<dim3(512), blk, 0, stream>>>(qkv, vT, attn);
    gemm_bt_bias<float, false><<<dim3(8192 / 128, 1024 / 128), blk, 0, stream>>>(
        attn, woutbf, bout, out, nullptr, 8192, 1024, 1024);
}

// Round 10
// 241.858 us; speedup vs baseline: 1.2402x; 1.2402x over previous
//
#include <hip/hip_runtime.h>
#include <stdint.h>

#define DEV __device__ __forceinline__

typedef unsigned short u16;
typedef __bf16 bf16x8 __attribute__((ext_vector_type(8)));
typedef __bf16 bf16x4 __attribute__((ext_vector_type(4)));
typedef float f32x4 __attribute__((ext_vector_type(4)));
typedef u16 u16x8 __attribute__((ext_vector_type(8)));

#define MFMA_BF16(A, B, C) __builtin_amdgcn_mfma_f32_16x16x32_bf16(A, B, C, 0, 0, 0)
#define EXP2(x) __builtin_amdgcn_exp2f(x)

DEV u16 f2bf(float f) {
    unsigned x;
    __builtin_memcpy(&x, &f, 4);
    unsigned r = (x + 0x7fffu + ((x >> 16) & 1u)) >> 16;  // RNE
    return (u16)r;
}

DEV u16 f2bf_fast(float f) {  // round-half-up; 2 VALU ops, used in attn hot loop
    unsigned x;
    __builtin_memcpy(&x, &f, 4);
    return (u16)((x + 0x8000u) >> 16);
}

DEV void storeC(u16* p, float v) { *p = f2bf(v); }
DEV void storeC(float* p, float v) { *p = v; }

// async global->LDS, 16B per lane. LDS dest must be wave-uniform base + lane*16.
DEV void async_copy16(const u16* g, u16* l) {
    __builtin_amdgcn_global_load_lds(
        (__attribute__((address_space(1))) unsigned int*)g,
        (__attribute__((address_space(3))) unsigned int*)l, 16, 0, 0);
}

// ---------------------------------------------------------------------------
// fused fp32 -> bf16 conversion of x | wqkv | wout into one contiguous dest.
// ---------------------------------------------------------------------------
constexpr int N_X = 8192 * 1024, N_WQ = 3072 * 1024, N_WO = 1024 * 1024;

__global__ __launch_bounds__(256)
void cvt_all(const float* __restrict__ x, const float* __restrict__ wq,
             const float* __restrict__ wo, u16* __restrict__ out) {
    const int i = (blockIdx.x * 256 + threadIdx.x) * 4;
    const float* src;
    if (i < N_X) src = x + i;
    else if (i < N_X + N_WQ) src = wq + (i - N_X);
    else src = wo + (i - N_X - N_WQ);
    const float4 v = *(const float4*)src;
    ushort4 o;
    o.x = f2bf(v.x);
    o.y = f2bf(v.y);
    o.z = f2bf(v.z);
    o.w = f2bf(v.w);
    *(ushort4*)(out + i) = o;
}

// ---------------------------------------------------------------------------
// C[M,N] = A[M,K] * Bw[N,K]^T + bias[N]; A,Bw bf16, bias fp32, fp32 accum.
// 128x128 tile, BK=64 as two 32-wide panels. EXACT r0 kernel — FROZEN.
// VSPLIT: cols >= 2048 (the V third of QKV) stored TRANSPOSED into vT.
// ---------------------------------------------------------------------------
template <typename OT, bool VSPLIT>
__global__ __launch_bounds__(256, 2)
void gemm_bt_bias(const u16* __restrict__ A, const u16* __restrict__ Bw,
                  const float* __restrict__ bias, OT* __restrict__ C,
                  u16* __restrict__ vT, int M, int N, int K) {
    __shared__ __attribute__((aligned(16))) u16 sA[2][128 * 32];
    __shared__ __attribute__((aligned(16))) u16 sB[2][128 * 32];

    const int tid  = threadIdx.x;
    const int lane = tid & 63;
    const int wave = tid >> 6;
    const int m0 = blockIdx.x * 128;   // M on x: XCD-local A reuse
    const int n0 = blockIdx.y * 128;
    const int wm = (wave & 1) * 64;
    const int wn = (wave >> 1) * 64;
    const int fr = lane & 15;
    const int q4 = lane >> 4;

    const int r0 = tid >> 2;
    const int c0 = (tid & 3) * 8;
    const u16* gA0 = A + (size_t)(m0 + r0) * K + c0;
    const u16* gA1 = A + (size_t)(m0 + 64 + r0) * K + c0;
    const u16* gB0 = Bw + (size_t)(n0 + r0) * K + c0;
    const u16* gB1 = Bw + (size_t)(n0 + 64 + r0) * K + c0;

    f32x4 acc[4][4];
#pragma unroll
    for (int i = 0; i < 4; i++)
#pragma unroll
        for (int j = 0; j < 4; j++) acc[i][j] = (f32x4){0.f, 0.f, 0.f, 0.f};

    for (int k0 = 0; k0 < K; k0 += 64) {
#pragma unroll
        for (int p = 0; p < 2; ++p) {  // two 32-wide K panels
            async_copy16(gA0 + k0 + p * 32, &sA[p][tid * 8]);
            async_copy16(gA1 + k0 + p * 32, &sA[p][2048 + tid * 8]);
            async_copy16(gB0 + k0 + p * 32, &sB[p][tid * 8]);
            async_copy16(gB1 + k0 + p * 32, &sB[p][2048 + tid * 8]);
        }
        __syncthreads();

#pragma unroll
        for (int p = 0; p < 2; ++p) {
            bf16x8 af[4], bfr[4];
#pragma unroll
            for (int i = 0; i < 4; i++)
                af[i] = *(const bf16x8*)&sA[p][(wm + i * 16 + fr) * 32 + q4 * 8];
#pragma unroll
            for (int j = 0; j < 4; j++)
                bfr[j] = *(const bf16x8*)&sB[p][(wn + j * 16 + fr) * 32 + q4 * 8];
#pragma unroll
            for (int i = 0; i < 4; i++)
#pragma unroll
                for (int j = 0; j < 4; j++)
                    acc[i][j] = MFMA_BF16(af[i], bfr[j], acc[i][j]);
        }
        __syncthreads();
    }

    // epilogue: C/D layout col=lane&15, row=quad*4+reg  [verified m89/m91]
#pragma unroll
    for (int j = 0; j < 4; j++) {
        const int col = n0 + wn + j * 16 + fr;
        const float bv = bias[col];
        if (VSPLIT && col >= 2048) {  // wave-uniform: col/16 uniform across fr
#pragma unroll
            for (int i = 0; i < 4; i++) {
                const int row = m0 + wm + i * 16 + q4 * 4;
                ushort4 o;
                o.x = f2bf(acc[i][j][0] + bv);
                o.y = f2bf(acc[i][j][1] + bv);
                o.z = f2bf(acc[i][j][2] + bv);
                o.w = f2bf(acc[i][j][3] + bv);
                *(ushort4*)&vT[(size_t)(col - 2048) * 8192 + row] = o;
            }
        } else {
#pragma unroll
            for (int i = 0; i < 4; i++) {
                const int row = m0 + wm + i * 16 + q4 * 4;
#pragma unroll
                for (int r = 0; r < 4; r++)
                    storeC(&C[(size_t)(row + r) * N + col], acc[i][j][r] + bv);
            }
        }
    }
}

// ---------------------------------------------------------------------------
// Flash attention, causal, S^T/O^T, FOUR CAUSAL-BALANCED Q-TILES, fixed-point
// softmax, r8 staging (dbuf swizzled K/V via reg-staged ds_write, 1 barrier).
// This round: IN-REGISTER P. In the S^T formulation lane (q4,fr) holds P for
// its own q-column fr at keys t*16+q4*4+r. Choosing the PV k-slot->key
// permutation sigma(ks*32+q4*8+j) = (2ks+j/4)*16 + q4*4 + (j%4) (legal: the
// contraction is key-permutation-invariant if V uses the same ordering;
// masking uses actual key ids which don't move) makes each lane's B-operand
// exactly its own 16 S values: P never touches LDS or shuffles. sP deleted;
// V fragments become two b64 reads (key halves 2ks*16, (2ks+1)*16 at +q4*4).
// r9 lesson: K/V must come via coalesced LDS staging, not per-wave gather.
// ---------------------------------------------------------------------------
constexpr int Lc = 2048, Dc = 1024;

__global__ __launch_bounds__(256, 2)
void attn_fa(const u16* __restrict__ qkv, const u16* __restrict__ vT,
             u16* __restrict__ outb) {
    __shared__ __attribute__((aligned(16))) u16 sK[2][64 * 64];   // [dbuf][key][d] swz
    __shared__ __attribute__((aligned(16))) u16 sVT[2][64 * 64];  // [dbuf][d][key] swz

    const int tid  = threadIdx.x;
    const int lane = tid & 63;
    const int wave = tid >> 6;
    const int fr = lane & 15;
    const int q4 = lane >> 4;
    const int f7 = fr & 7;  // read-side swizzle key (rows are t*16+fr -> row&7 == fr&7)

    const int id = blockIdx.x;               // 0..511
    const int g  = (id & 7) + 8 * (id >> 6); // (b,h) group; XCD = g & 7
    const int bx = (id >> 3) & 7;            // 0..7
    const int h = g & 15;
    const int b = g >> 4;
    const int qA = bx, qB = 15 - bx, qC = 16 + bx, qD = 31 - bx;

    constexpr float CEXP = 0.18033688011112042f;   // 0.125 * log2(e)
    constexpr float MOFF = 16.0f * CEXP;           // fixed rescale point m=16

    bf16x8 qfA[2], qfB[2], qfC[2], qfD[2];
#define LOADQ(qf, qblk)                                                     \
    {                                                                       \
        const int qrow = (qblk) * 64 + wave * 16 + fr;                      \
        const u16* qp = qkv + ((size_t)(b * Lc + qrow) * 3) * Dc + h * 64;  \
        qf[0] = *(const bf16x8*)(qp + q4 * 8);                              \
        qf[1] = *(const bf16x8*)(qp + 32 + q4 * 8);                         \
    }
    LOADQ(qfA, qA) LOADQ(qfB, qB) LOADQ(qfC, qC) LOADQ(qfD, qD)
#undef LOADQ

    f32x4 oA[4], oB[4], oC[4], oD[4];
#pragma unroll
    for (int t = 0; t < 4; t++) {
        oA[t] = (f32x4){0.f, 0.f, 0.f, 0.f};
        oB[t] = (f32x4){0.f, 0.f, 0.f, 0.f};
        oC[t] = (f32x4){0.f, 0.f, 0.f, 0.f};
        oD[t] = (f32x4){0.f, 0.f, 0.f, 0.f};
    }
    float lA = 0.f, lB = 0.f, lC = 0.f, lD = 0.f;  // per-lane partial sums

    const int q_local = wave * 16 + fr;

    // staging: thread covers rows rr, rr+32; 16B chunk oo; swizzled write.
    const int rr = tid >> 3;
    const int oo = tid & 7;
    const int wchk = (oo ^ (rr & 7)) * 8;  // physical chunk (u16 units)
    const u16* kg = qkv + ((size_t)(b * Lc) * 3 + 1) * Dc + h * 64 + oo * 8;  // + tok*3072
    const u16* vg = vT + (size_t)(h * 64) * 8192 + b * Lc + oo * 8;           // + d*8192 + key

    u16x8 kr[2], vr[2];
#define LOADT(jb1)                                                                \
    _Pragma("unroll") for (int c = 0; c < 2; ++c) {                               \
        kr[c] = *(const u16x8*)(kg + (size_t)((jb1) * 64 + c * 32 + rr) * 3072);  \
        vr[c] = *(const u16x8*)(vg + (size_t)(c * 32 + rr) * 8192 + (jb1) * 64);  \
    }
#define WRT(bufi)                                                                 \
    _Pragma("unroll") for (int c = 0; c < 2; ++c) {                               \
        *(u16x8*)&sK[bufi][(c * 32 + rr) * 64 + wchk] = kr[c];                    \
        *(u16x8*)&sVT[bufi][(c * 32 + rr) * 64 + wchk] = vr[c];                   \
    }

    // per-tile: S^T = K Q^T (kf regs), fixed-point softmax, pack P INTO REGS:
    // pf[ks] = {S[2ks][0..3], S[2ks+1][0..3]} as bf16 — lane-local, no LDS.
#define DO_TILE(qf, lS, pf, qblk)                                           \
    {                                                                       \
        f32x4 S[4];                                                         \
        _Pragma("unroll") for (int t = 0; t < 4; t++) {                     \
            S[t] = (f32x4){0.f, 0.f, 0.f, 0.f};                             \
            S[t] = MFMA_BF16(kf[t][0], qf[0], S[t]);                        \
            S[t] = MFMA_BF16(kf[t][1], qf[1], S[t]);                        \
        }                                                                   \
        if (jb == (qblk)) {                                                 \
            _Pragma("unroll") for (int t = 0; t < 4; t++)                   \
                _Pragma("unroll") for (int r = 0; r < 4; r++)               \
                    if (t * 16 + q4 * 4 + r > q_local) S[t][r] = -1e30f;    \
        }                                                                   \
        _Pragma("unroll") for (int t = 0; t < 4; t++)                       \
            _Pragma("unroll") for (int r = 0; r < 4; r++) {                 \
                const float p = EXP2(__builtin_fmaf(S[t][r], CEXP, -MOFF)); \
                S[t][r] = p;                                                \
                lS += p;                                                    \
            }                                                               \
        _Pragma("unroll") for (int ks = 0; ks < 2; ++ks) {                  \
            u16x8 w;                                                        \
            _Pragma("unroll") for (int j = 0; j < 4; j++) {                 \
                w[j] = f2bf_fast(S[2 * ks][j]);                             \
                w[4 + j] = f2bf_fast(S[2 * ks + 1][j]);                     \
            }                                                               \
            __builtin_memcpy(&pf[ks], &w, 16);                              \
        }                                                                   \
    }

    // prologue: tile 0 written, tile 1 in regs
    LOADT(0);
    WRT(0);
    LOADT(1);
    __syncthreads();

    for (int jb = 0; jb <= qD; ++jb) {
        const u16* cK = sK[jb & 1];
        const u16* cV = sVT[jb & 1];

        if (jb < qD) WRT((jb & 1) ^ 1);   // tile jb+1 regs -> other buffer
        if (jb + 2 <= qD) LOADT(jb + 2);  // regs <- tile jb+2 (full iter of slack)

        const bool doA = (jb <= qA);  // wave-uniform
        const bool doB = (jb <= qB);
        const bool doC = (jb <= qC);

        // K fragments for S^T = K Q^T (shared across the 4 q-tiles)
        bf16x8 kf[4][2];
#pragma unroll
        for (int t = 0; t < 4; t++) {
            const int row = (t * 16 + fr) * 64;
            kf[t][0] = *(const bf16x8*)&cK[row + (q4 ^ f7) * 8];
            kf[t][1] = *(const bf16x8*)&cK[row + ((4 + q4) ^ f7) * 8];
        }

        bf16x8 pfA[2], pfB[2], pfC[2], pfD[2];
        DO_TILE(qfD, lD, pfD, qD);
        if (doC) DO_TILE(qfC, lC, pfC, qC);
        if (doB) DO_TILE(qfB, lB, pfB, qB);
        if (doA) DO_TILE(qfA, lA, pfA, qA);

        // O^T += V^T P^T with permuted key order: lane q4's V k-slots j are
        // keys (2ks+j/4)*16 + q4*4 + (j%4) -> two b64 reads per fragment.
#pragma unroll
        for (int ks = 0; ks < 2; ++ks) {
#pragma unroll
            for (int t = 0; t < 4; t++) {
                const int rowb = (t * 16 + fr) * 64;
                const int sub = (q4 & 1) * 4;
                const bf16x4 vlo = *(const bf16x4*)
                    &cV[rowb + (((4 * ks + (q4 >> 1))) ^ f7) * 8 + sub];
                const bf16x4 vhi = *(const bf16x4*)
                    &cV[rowb + (((4 * ks + 2 + (q4 >> 1))) ^ f7) * 8 + sub];
                const bf16x8 vf = __builtin_shufflevector(vlo, vhi, 0, 1, 2, 3, 4, 5, 6, 7);
                oD[t] = MFMA_BF16(vf, pfD[ks], oD[t]);
                if (doC) oC[t] = MFMA_BF16(vf, pfC[ks], oC[t]);
                if (doB) oB[t] = MFMA_BF16(vf, pfB[ks], oB[t]);
                if (doA) oA[t] = MFMA_BF16(vf, pfA[ks], oA[t]);
            }
        }
        __syncthreads();  // single barrier: seals this iter's reads & writes
    }
#undef DO_TILE
#undef LOADT
#undef WRT

    // epilogue: reduce per-lane l once, then O^T -> packed ushort4
#define WR_OUT(oS, lS, qblk)                                                      \
    {                                                                             \
        float lt = lS;                                                            \
        lt += __shfl_xor(lt, 16);                                                 \
        lt += __shfl_xor(lt, 32);                                                 \
        const float rl = 1.0f / lt;                                               \
        u16* orow =                                                               \
            outb + (size_t)(b * Lc + (qblk) * 64 + wave * 16 + fr) * Dc + h * 64; \
        _Pragma("unroll") for (int t = 0; t < 4; t++) {                           \
            ushort4 o;                                                            \
            o.x = f2bf(oS[t][0] * rl);                                            \
            o.y = f2bf(oS[t][1] * rl);                                            \
            o.z = f2bf(oS[t][2] * rl);                                            \
            o.w = f2bf(oS[t][3] * rl);                                            \
            *(ushort4*)(orow + t * 16 + q4 * 4) = o;                              \
        }                                                                         \
    }
    WR_OUT(oA, lA, qA)
    WR_OUT(oB, lB, qB)
    WR_OUT(oC, lC, qC)
    WR_OUT(oD, lD, qD)
#undef WR_OUT
}

// ---------------------------------------------------------------------------
extern "C" void kernel_launch(void* const* d_in, const int* in_sizes, int n_in,
                              void* d_out, int out_size, void* d_ws, size_t ws_size,
                              hipStream_t stream) {
    const float* x    = (const float*)d_in[0];  // [4,2048,1024] fp32
    const float* wqkv = (const float*)d_in[1];  // [3072,1024]
    const float* bqkv = (const float*)d_in[2];  // [3072]
    const float* wout = (const float*)d_in[3];  // [1024,1024]
    const float* bout = (const float*)d_in[4];  // [1024]
    float* out = (float*)d_out;                 // [4,2048,1024] fp32

    u16* qkv    = (u16*)d_ws;                       // [8192,3072] bf16 (V third unused)
    u16* attn   = qkv + (size_t)8192 * 3072;        // [8192,1024] bf16
    u16* xbf    = attn + (size_t)8192 * 1024;       // [8192,1024] bf16
    u16* wqkvbf = xbf + (size_t)8192 * 1024;        // [3072,1024] bf16
    u16* woutbf = wqkvbf + (size_t)3072 * 1024;     // [1024,1024] bf16
    u16* vT     = woutbf + (size_t)1024 * 1024;     // [1024, 8192] bf16 (V transposed)

    dim3 blk(256);
    cvt_all<<<(N_X + N_WQ + N_WO) / 1024, blk, 0, stream>>>(x, wqkv, wout, xbf);

    gemm_bt_bias<u16, true><<<dim3(8192 / 128, 3072 / 128), blk, 0, stream>>>(
        xbf, wqkvbf, bqkv, qkv, vT, 8192, 3072, 1024);
    attn_fa<<<dim3(512), blk, 0, stream>>>(qkv, vT, attn);
    gemm_bt_bias<float, false><<<dim3(8192 / 128, 1024 / 128), blk, 0, stream>>>(
        attn, woutbf, bout, out, nullptr, 8192, 1024, 1024);
}